// Round 5
// baseline (3589.149 us; speedup 1.0000x reference)
//
#include <hip/hip_runtime.h>
#include <math.h>

#define BATCH 8192
#define FEAT  64
#define HID   1024
#define NSTEPS 8
#define RM    32            // batch rows per block
#define NBLK  (BATCH / RM)  // 256 blocks = 1 per CU

typedef __attribute__((ext_vector_type(8))) short bf16x8;
typedef __attribute__((ext_vector_type(4))) float f32x4;
typedef __attribute__((ext_vector_type(2))) unsigned int u32x2;
typedef unsigned short u16;
typedef unsigned int u32;

__device__ __forceinline__ float bf2f(u16 u) {
    u32 v = ((u32)u) << 16;
    return __builtin_bit_cast(float, v);
}
__device__ __forceinline__ u16 f2bf(float f) {
    u32 v = __builtin_bit_cast(u32, f);
    v += 0x7FFFu + ((v >> 16) & 1u);
    return (u16)(v >> 16);
}
__device__ __forceinline__ u32 pack2(u16 a, u16 b) { return (u32)a | ((u32)b << 16); }

// storage swizzle (global weights AND LDS activations): within each 64-elem
// window of row m, 8-elem slot s -> s ^ (m&7). Producers write swizzled;
// fragment reads / epilogue RMWs use the same XOR. 2-way bank aliasing = free.
__device__ __host__ __forceinline__ size_t swz_off(int m, int k, int K) {
    int s = (k >> 3) & 7;
    return (size_t)m * K + (k & ~63) + (((s ^ m) & 7) << 3) + (k & 7);
}
__device__ __forceinline__ int ldso(int m, int j) {   // 1024-wide LDS tiles
    return m * HID + (j & ~63) + (((((j >> 3)) ^ m) & 7) << 3) + (j & 7);
}
__device__ __forceinline__ int lds64(int m, int f) {  // 64-wide LDS tiles
    return m * 64 + (((((f >> 3)) ^ m) & 7) << 3) + (f & 7);
}
__device__ __forceinline__ float tanh_fast(float x) {
    x = fminf(20.f, fmaxf(-20.f, x));
    float e = __builtin_amdgcn_exp2f(x * 2.8853900817779268f); // e^(2x)
    return 1.f - 2.f * __builtin_amdgcn_rcpf(e + 1.f);
}

__global__ __launch_bounds__(512, 2)
void ffjord_mega(const float* __restrict__ x,
                 const float* __restrict__ eps,
                 const u16* __restrict__ w1tb,   // [1024][64]  = W1[:64]^T  swz
                 const float* __restrict__ w1x,  // W1 row 64 (t coeff) fp32 [1024]
                 const float* __restrict__ b1,
                 const u16* __restrict__ w2t,    // [1024][1024] = W2^T swz
                 const u16* __restrict__ w2n,    // [1024][1024] = W2   swz
                 const float* __restrict__ b2,
                 const u16* __restrict__ w3n,    // [1024][64]  = W3    swz
                 const u16* __restrict__ w3t,    // [64][1024]  = W3^T  swz
                 const float* __restrict__ b3,
                 float* __restrict__ outp)
{
    __shared__ __align__(16) u16 h1s[RM * HID];   // h1, later me=(1-h1^2)*E
    __shared__ __align__(16) u16 h2s[RM * HID];   // h2, later g2
    __shared__ __align__(16) u16 xins[RM * 64];   // current xin (bf16, swz)
    __shared__ __align__(16) u16 epss[RM * 64];   // eps tile (bf16, swz)
    __shared__ float red[RM * 33];                // trace reduction

    const int tid = threadIdx.x;
    const int wv = tid >> 6, lane = tid & 63;
    const int l15 = lane & 15, l4 = lane >> 4;
    const int m0 = blockIdx.x * RM;

    // per-thread state ownership (matches G3 C/D layout):
    const int sm = (wv & 1) * 16 + l15;         // batch row within tile
    const int sf = (wv >> 1) * 16 + l4 * 4;     // 4 consecutive features

    float yxr[4], axr[4];
    {
        f32x4 xv = *(const f32x4*)(x + (size_t)(m0 + sm) * FEAT + sf);
        f32x4 ev = *(const f32x4*)(eps + (size_t)(m0 + sm) * FEAT + sf);
#pragma unroll
        for (int r = 0; r < 4; r++) yxr[r] = xv[r];
        u32x2 px = { pack2(f2bf(xv[0]), f2bf(xv[1])), pack2(f2bf(xv[2]), f2bf(xv[3])) };
        u32x2 pe = { pack2(f2bf(ev[0]), f2bf(ev[1])), pack2(f2bf(ev[2]), f2bf(ev[3])) };
        *(u32x2*)&xins[lds64(sm, sf)] = px;
        *(u32x2*)&epss[lds64(sm, sf)] = pe;
    }
    float yl = 0.f, al = 0.f;                   // logdet state (tid<32 lanes own it)
    __syncthreads();

    const float h = 1.f / NSTEPS, h6 = h / 6.f;

    for (int s = 0; s < NSTEPS; s++) {
        for (int st = 0; st < 4; st++) {
            const float ts = s * h + ((st == 1 || st == 2) ? 0.5f * h : (st == 3 ? h : 0.f));

            // ---- G1: h1^T = W1^T @ xin^T, tanh(+b1 + t*w1x) -> h1s ----
#pragma unroll
            for (int jj = 0; jj < 8; jj++) {
                const int jr = (wv * 8 + jj) * 16;
                f32x4 bb = *(const f32x4*)(b1 + jr + l4 * 4);
                f32x4 wt = *(const f32x4*)(w1x + jr + l4 * 4);
#pragma unroll
                for (int mt = 0; mt < 2; mt++) {
                    f32x4 acc = {};
#pragma unroll
                    for (int ks = 0; ks < 2; ks++) {
                        const int k0 = ks * 32 + l4 * 8;
                        bf16x8 a = *(const bf16x8*)(w1tb + swz_off(jr + l15, k0, 64));
                        bf16x8 b = *(const bf16x8*)&xins[lds64(mt * 16 + l15, k0)];
                        acc = __builtin_amdgcn_mfma_f32_16x16x32_bf16(a, b, acc, 0, 0, 0);
                    }
                    u32x2 pw = {
                        pack2(f2bf(tanh_fast(acc[0] + bb[0] + ts * wt[0])),
                              f2bf(tanh_fast(acc[1] + bb[1] + ts * wt[1]))),
                        pack2(f2bf(tanh_fast(acc[2] + bb[2] + ts * wt[2])),
                              f2bf(tanh_fast(acc[3] + bb[3] + ts * wt[3]))) };
                    *(u32x2*)&h1s[ldso(mt * 16 + l15, jr + l4 * 4)] = pw;
                }
            }
            __syncthreads();  // B1: h1s ready

            // ---- G2: h2^T = W2^T @ h1^T, tanh(+b2) -> h2s ----
            {
                f32x4 acc2[8][2] = {};
#pragma unroll 2
                for (int ks = 0; ks < 32; ks++) {
                    const int k0 = ks * 32 + l4 * 8;
                    bf16x8 a[8], b[2];
#pragma unroll
                    for (int jj = 0; jj < 8; jj++)
                        a[jj] = *(const bf16x8*)(w2t + swz_off((wv * 8 + jj) * 16 + l15, k0, HID));
#pragma unroll
                    for (int mt = 0; mt < 2; mt++)
                        b[mt] = *(const bf16x8*)&h1s[ldso(mt * 16 + l15, k0)];
#pragma unroll
                    for (int jj = 0; jj < 8; jj++)
#pragma unroll
                        for (int mt = 0; mt < 2; mt++)
                            acc2[jj][mt] = __builtin_amdgcn_mfma_f32_16x16x32_bf16(
                                a[jj], b[mt], acc2[jj][mt], 0, 0, 0);
                }
#pragma unroll
                for (int jj = 0; jj < 8; jj++) {
                    const int jr = (wv * 8 + jj) * 16;
                    f32x4 bb = *(const f32x4*)(b2 + jr + l4 * 4);
#pragma unroll
                    for (int mt = 0; mt < 2; mt++) {
                        u32x2 pw = {
                            pack2(f2bf(tanh_fast(acc2[jj][mt][0] + bb[0])),
                                  f2bf(tanh_fast(acc2[jj][mt][1] + bb[1]))),
                            pack2(f2bf(tanh_fast(acc2[jj][mt][2] + bb[2])),
                                  f2bf(tanh_fast(acc2[jj][mt][3] + bb[3]))) };
                        *(u32x2*)&h2s[ldso(mt * 16 + l15, jr + l4 * 4)] = pw;
                    }
                }
            }
            __syncthreads();  // B2: h2s ready

            // ---- G3: dx^T = W3^T @ h2^T (1 tile/wave, dx kept in regs) ----
            f32x4 acc3 = {};
            {
                const int fr = (wv >> 1) * 16;
                const int mt3 = wv & 1;
#pragma unroll 4
                for (int ks = 0; ks < 32; ks++) {
                    const int k0 = ks * 32 + l4 * 8;
                    bf16x8 a = *(const bf16x8*)(w3t + swz_off(fr + l15, k0, HID));
                    bf16x8 b = *(const bf16x8*)&h2s[ldso(mt3 * 16 + l15, k0)];
                    acc3 = __builtin_amdgcn_mfma_f32_16x16x32_bf16(a, b, acc3, 0, 0, 0);
                }
            }
            __syncthreads();  // B3: all h2s/h1s readers done -> RMW allowed

            // ---- merged: g3^T = W3 @ eps^T -> g2 = g3*(1-h2^2) RMW h2s
            //              E^T  = W1^T @ eps^T -> me = (1-h1^2)*E RMW h1s ----
#pragma unroll
            for (int jj = 0; jj < 8; jj++) {
                const int jr = (wv * 8 + jj) * 16;
#pragma unroll
                for (int mt = 0; mt < 2; mt++) {
                    f32x4 ag = {}, ae = {};
#pragma unroll
                    for (int ks = 0; ks < 2; ks++) {
                        const int k0 = ks * 32 + l4 * 8;
                        bf16x8 be = *(const bf16x8*)&epss[lds64(mt * 16 + l15, k0)];
                        bf16x8 a3 = *(const bf16x8*)(w3n + swz_off(jr + l15, k0, 64));
                        bf16x8 a1 = *(const bf16x8*)(w1tb + swz_off(jr + l15, k0, 64));
                        ag = __builtin_amdgcn_mfma_f32_16x16x32_bf16(a3, be, ag, 0, 0, 0);
                        ae = __builtin_amdgcn_mfma_f32_16x16x32_bf16(a1, be, ae, 0, 0, 0);
                    }
                    const int off = ldso(mt * 16 + l15, jr + l4 * 4);
                    u32x2 hw = *(u32x2*)&h2s[off];
                    u32x2 h1w = *(u32x2*)&h1s[off];
                    float h2v[4] = { bf2f((u16)(hw[0] & 0xffff)), bf2f((u16)(hw[0] >> 16)),
                                     bf2f((u16)(hw[1] & 0xffff)), bf2f((u16)(hw[1] >> 16)) };
                    float h1v[4] = { bf2f((u16)(h1w[0] & 0xffff)), bf2f((u16)(h1w[0] >> 16)),
                                     bf2f((u16)(h1w[1] & 0xffff)), bf2f((u16)(h1w[1] >> 16)) };
                    u32x2 pg = {
                        pack2(f2bf(ag[0] * (1.f - h2v[0] * h2v[0])),
                              f2bf(ag[1] * (1.f - h2v[1] * h2v[1]))),
                        pack2(f2bf(ag[2] * (1.f - h2v[2] * h2v[2])),
                              f2bf(ag[3] * (1.f - h2v[3] * h2v[3]))) };
                    u32x2 pm = {
                        pack2(f2bf(ae[0] * (1.f - h1v[0] * h1v[0])),
                              f2bf(ae[1] * (1.f - h1v[1] * h1v[1]))),
                        pack2(f2bf(ae[2] * (1.f - h1v[2] * h1v[2])),
                              f2bf(ae[3] * (1.f - h1v[3] * h1v[3]))) };
                    *(u32x2*)&h2s[off] = pg;
                    *(u32x2*)&h1s[off] = pm;
                }
            }
            __syncthreads();  // B4: g2 (h2s) + me (h1s) ready

            // ---- G5: g0^T = W2 @ g2^T; trace partial = sum g0*me ----
            {
                f32x4 acc5[8][2] = {};
#pragma unroll 2
                for (int ks = 0; ks < 32; ks++) {
                    const int k0 = ks * 32 + l4 * 8;
                    bf16x8 a[8], b[2];
#pragma unroll
                    for (int jj = 0; jj < 8; jj++)
                        a[jj] = *(const bf16x8*)(w2n + swz_off((wv * 8 + jj) * 16 + l15, k0, HID));
#pragma unroll
                    for (int mt = 0; mt < 2; mt++)
                        b[mt] = *(const bf16x8*)&h2s[ldso(mt * 16 + l15, k0)];
#pragma unroll
                    for (int jj = 0; jj < 8; jj++)
#pragma unroll
                        for (int mt = 0; mt < 2; mt++)
                            acc5[jj][mt] = __builtin_amdgcn_mfma_f32_16x16x32_bf16(
                                a[jj], b[mt], acc5[jj][mt], 0, 0, 0);
                }
                float ts0 = 0.f, ts1 = 0.f;
#pragma unroll
                for (int jj = 0; jj < 8; jj++) {
                    const int jr = (wv * 8 + jj) * 16;
#pragma unroll
                    for (int mt = 0; mt < 2; mt++) {
                        const int off = ldso(mt * 16 + l15, jr + l4 * 4);
                        u32x2 mw = *(u32x2*)&h1s[off];
                        float t0 = acc5[jj][mt][0] * bf2f((u16)(mw[0] & 0xffff))
                                 + acc5[jj][mt][1] * bf2f((u16)(mw[0] >> 16))
                                 + acc5[jj][mt][2] * bf2f((u16)(mw[1] & 0xffff))
                                 + acc5[jj][mt][3] * bf2f((u16)(mw[1] >> 16));
                        if (mt == 0) ts0 += t0; else ts1 += t0;
                    }
                }
                red[l15 * 33 + wv * 4 + l4] = ts0;
                red[(16 + l15) * 33 + wv * 4 + l4] = ts1;
            }
            __syncthreads();  // B5: red ready

            // ---- RK4 combine (in-register state) ----
            {
                const float wacc = (st == 1 || st == 2) ? 2.f : 1.f;
                const float wtmp = (st < 2) ? 0.5f * h : h;
                f32x4 b3v = *(const f32x4*)(b3 + sf);
                float nx[4];
#pragma unroll
                for (int r = 0; r < 4; r++) {
                    float d = acc3[r] + b3v[r];
                    axr[r] = (st == 0 ? 0.f : axr[r]) + wacc * d;
                    if (st == 3) { yxr[r] += h6 * axr[r]; nx[r] = yxr[r]; }
                    else nx[r] = yxr[r] + wtmp * d;
                }
                u32x2 px = { pack2(f2bf(nx[0]), f2bf(nx[1])), pack2(f2bf(nx[2]), f2bf(nx[3])) };
                *(u32x2*)&xins[lds64(sm, sf)] = px;
                if (tid < RM) {
                    float tr = 0.f;
#pragma unroll
                    for (int c = 0; c < 32; c++) tr += red[tid * 33 + c];
                    al = (st == 0 ? 0.f : al) + wacc * (-tr);
                    if (st == 3) yl += h6 * al;
                }
            }
            __syncthreads();  // B6: xins ready for next eval
        }
    }

    // ---- output ----
    {
        f32x4 zv = { yxr[0], yxr[1], yxr[2], yxr[3] };
        *(f32x4*)(outp + (size_t)(m0 + sm) * FEAT + sf) = zv;
        if (tid < RM) outp[(size_t)BATCH * FEAT + m0 + tid] = yl;
    }
}

// ---- weight prep (once per call; tiny) ----
__global__ void cast_bf(const float* __restrict__ in, u16* __restrict__ out,
                        int n, int W)
{
    int i = blockIdx.x * 256 + threadIdx.x;
    if (i < n) out[swz_off(i / W, i % W, W)] = f2bf(in[i]);
}

// in [R'][C'] fp32 -> out [C'][R'] bf16 swizzled (out rows = in cols)
__global__ void transpose_cast(const float* __restrict__ in, u16* __restrict__ out,
                               int R, int C)
{
    __shared__ float t[32][33];
    int bx = blockIdx.x * 32, by = blockIdx.y * 32;
    int tx = threadIdx.x, ty = threadIdx.y;  // block (32,8)
    for (int i = 0; i < 32; i += 8)
        t[ty + i][tx] = in[(size_t)(by + ty + i) * C + bx + tx];
    __syncthreads();
    for (int i = 0; i < 32; i += 8)
        out[swz_off(bx + ty + i, by + tx, R)] = f2bf(t[tx][ty + i]);
}

extern "C" void kernel_launch(void* const* d_in, const int* in_sizes, int n_in,
                              void* d_out, int out_size, void* d_ws, size_t ws_size,
                              hipStream_t stream)
{
    const float* x   = (const float*)d_in[0];
    const float* W1  = (const float*)d_in[1];
    const float* b1  = (const float*)d_in[2];
    const float* W2  = (const float*)d_in[3];
    const float* b2  = (const float*)d_in[4];
    const float* W3  = (const float*)d_in[5];
    const float* b3  = (const float*)d_in[6];
    const float* eps = (const float*)d_in[7];
    float* out = (float*)d_out;

    char* ws = (char*)d_ws;
    size_t o = 0;
    auto alloc = [&](size_t bytes) { char* p = ws + o; o += (bytes + 255) & ~(size_t)255; return p; };

    u16* w1tb = (u16*)alloc((size_t)HID * FEAT * 2);   // [1024][64] W1[:64]^T
    u16* w2t  = (u16*)alloc((size_t)HID * HID * 2);    // W2^T
    u16* w2n  = (u16*)alloc((size_t)HID * HID * 2);    // W2
    u16* w3n  = (u16*)alloc((size_t)HID * FEAT * 2);   // [1024][64] W3
    u16* w3t  = (u16*)alloc((size_t)FEAT * HID * 2);   // [64][1024] W3^T

    const dim3 blk(256);
    cast_bf<<<dim3((HID * HID + 255) / 256), blk, 0, stream>>>(W2, w2n, HID * HID, HID);
    cast_bf<<<dim3((HID * FEAT + 255) / 256), blk, 0, stream>>>(W3, w3n, HID * FEAT, FEAT);
    transpose_cast<<<dim3(HID / 32, HID / 32), dim3(32, 8), 0, stream>>>(W2, w2t, HID, HID);
    transpose_cast<<<dim3(HID / 32, FEAT / 32), dim3(32, 8), 0, stream>>>(W1, w1tb, FEAT, HID);
    transpose_cast<<<dim3(FEAT / 32, HID / 32), dim3(32, 8), 0, stream>>>(W3, w3t, HID, FEAT);

    ffjord_mega<<<dim3(NBLK), dim3(512), 0, stream>>>(
        x, eps,
        w1tb, W1 + (size_t)FEAT * HID, b1,
        w2t, w2n, b2,
        w3n, w3t, b3,
        out);
}

// Round 6
// 3559.706 us; speedup vs baseline: 1.0083x; 1.0083x over previous
//
#include <hip/hip_runtime.h>
#include <math.h>

#define BATCH 8192
#define FEAT  64
#define HID   1024
#define NSTEPS 8
#define RM    32            // batch rows per block
#define NBLK  (BATCH / RM)  // 256 blocks = 1 per CU

typedef __attribute__((ext_vector_type(8))) short bf16x8;
typedef __attribute__((ext_vector_type(4))) float f32x4;
typedef __attribute__((ext_vector_type(2))) unsigned int u32x2;
typedef unsigned short u16;
typedef unsigned int u32;

__device__ __forceinline__ float bf2f(u16 u) {
    u32 v = ((u32)u) << 16;
    return __builtin_bit_cast(float, v);
}
__device__ __forceinline__ u16 f2bf(float f) {
    u32 v = __builtin_bit_cast(u32, f);
    v += 0x7FFFu + ((v >> 16) & 1u);
    return (u16)(v >> 16);
}
__device__ __forceinline__ u32 pack2(u16 a, u16 b) { return (u32)a | ((u32)b << 16); }

// storage swizzle (global weights AND LDS activations): within each 64-elem
// window of row m, 8-elem slot s -> s ^ (m&7).
__device__ __host__ __forceinline__ size_t swz_off(int m, int k, int K) {
    int s = (k >> 3) & 7;
    return (size_t)m * K + (k & ~63) + (((s ^ m) & 7) << 3) + (k & 7);
}
__device__ __forceinline__ int ldso(int m, int j) {   // 1024-wide LDS tiles
    return m * HID + (j & ~63) + (((((j >> 3)) ^ m) & 7) << 3) + (j & 7);
}
__device__ __forceinline__ int lds64(int m, int f) {  // 64-wide LDS tiles
    return m * 64 + (((((f >> 3)) ^ m) & 7) << 3) + (f & 7);
}
__device__ __forceinline__ float tanh_fast(float x) {
    x = fminf(20.f, fmaxf(-20.f, x));
    float e = __builtin_amdgcn_exp2f(x * 2.8853900817779268f); // e^(2x)
    return 1.f - 2.f * __builtin_amdgcn_rcpf(e + 1.f);
}

__global__ __launch_bounds__(512, 2)
void ffjord_mega(const float* __restrict__ x,
                 const float* __restrict__ eps,
                 const u16* __restrict__ w1tb,   // [1024][64]  = W1[:64]^T  swz
                 const float* __restrict__ w1x,  // W1 row 64 (t coeff) fp32 [1024]
                 const float* __restrict__ b1,
                 const u16* __restrict__ w2t,    // [1024][1024] = W2^T swz
                 const float* __restrict__ b2,
                 const u16* __restrict__ w3n,    // [1024][64]  = W3    swz
                 const u16* __restrict__ w3t,    // [64][1024]  = W3^T  swz
                 const float* __restrict__ b3,
                 float* __restrict__ outp)
{
    __shared__ __align__(16) u16 h1s[RM * HID];   // h1, later me=(1-h1^2)*E
    __shared__ __align__(16) u16 h2s[RM * HID];   // h2 (read-only after G2)
    __shared__ __align__(16) u16 xins[RM * 64];   // current xin (bf16, swz)
    __shared__ __align__(16) u16 epss[RM * 64];   // eps tile (bf16, swz)
    __shared__ float red[RM * 33];                // trace reduction

    const int tid = threadIdx.x;
    const int wv = tid >> 6, lane = tid & 63;
    const int l15 = lane & 15, l4 = lane >> 4;
    const int m0 = blockIdx.x * RM;

    // per-thread state ownership (matches G3 C/D layout):
    const int sm = (wv & 1) * 16 + l15;         // batch row within tile
    const int sf = (wv >> 1) * 16 + l4 * 4;     // 4 consecutive features

    float yxr[4], axr[4];
    {
        f32x4 xv = *(const f32x4*)(x + (size_t)(m0 + sm) * FEAT + sf);
        f32x4 ev = *(const f32x4*)(eps + (size_t)(m0 + sm) * FEAT + sf);
#pragma unroll
        for (int r = 0; r < 4; r++) yxr[r] = xv[r];
        u32x2 px = { pack2(f2bf(xv[0]), f2bf(xv[1])), pack2(f2bf(xv[2]), f2bf(xv[3])) };
        u32x2 pe = { pack2(f2bf(ev[0]), f2bf(ev[1])), pack2(f2bf(ev[2]), f2bf(ev[3])) };
        *(u32x2*)&xins[lds64(sm, sf)] = px;
        *(u32x2*)&epss[lds64(sm, sf)] = pe;
    }
    float yl = 0.f, al = 0.f;                   // logdet state (tid<32 lanes own it)
    __syncthreads();

    const float h = 1.f / NSTEPS, h6 = h / 6.f;

    f32x4 acc[8][2];          // shared accumulator for G2 / P5
    u32x2 g2p[8][2];          // g2 tiles, packed bf16, register-resident
    bf16x8 aA[8], aB[8], bA[2], bB[2];

    // w2t fragment address for K-step ks (row-swizzled 16B slots)
    auto w2addr = [&](int jj, int ks) -> const char* {
        int row = (wv * 8 + jj) * 16 + l15;
        return (const char*)w2t + (size_t)row * 2048 + ((ks >> 1) << 7)
               + (((((ks << 2) | l4) ^ row) & 7) << 4);
    };
    auto loadA = [&](bf16x8 (&dst)[8], int ks) {
#pragma unroll
        for (int jj = 0; jj < 8; jj++) dst[jj] = *(const bf16x8*)w2addr(jj, ks);
    };
    auto loadB = [&](bf16x8 (&dst)[2], int ks, const u16* src) {
#pragma unroll
        for (int mt = 0; mt < 2; mt++)
            dst[mt] = *(const bf16x8*)&src[ldso(mt * 16 + l15, ks * 32 + l4 * 8)];
    };
    auto mfma16A = [&](bf16x8 (&a)[8], bf16x8 (&b)[2]) {
#pragma unroll
        for (int jj = 0; jj < 8; jj++)
#pragma unroll
            for (int mt = 0; mt < 2; mt++)
                acc[jj][mt] = __builtin_amdgcn_mfma_f32_16x16x32_bf16(
                    a[jj], b[mt], acc[jj][mt], 0, 0, 0);
    };
    // pipelined 1024-K GEMM: acc = W2^T-frags x src-frags
    auto big_gemm = [&](const u16* src) {
#pragma unroll
        for (int jj = 0; jj < 8; jj++)
#pragma unroll
            for (int mt = 0; mt < 2; mt++) acc[jj][mt] = (f32x4){};
        loadA(aA, 0); loadB(bA, 0, src);
        for (int ks = 0; ks < 32; ks += 2) {
            loadA(aB, ks + 1); loadB(bB, ks + 1, src);
            mfma16A(aA, bA);
            if (ks + 2 < 32) { loadA(aA, ks + 2); loadB(bA, ks + 2, src); }
            mfma16A(aB, bB);
        }
    };

    for (int s = 0; s < NSTEPS; s++) {
        for (int st = 0; st < 4; st++) {
            const float ts = s * h + ((st == 1 || st == 2) ? 0.5f * h : (st == 3 ? h : 0.f));

            // ---- G1: h1^T = W1^T @ xin^T, tanh(+b1 + t*w1x) -> h1s ----
#pragma unroll
            for (int jj = 0; jj < 8; jj++) {
                const int jr = (wv * 8 + jj) * 16;
                const int rw = jr + l15;
                const char* p1 = (const char*)w1tb + rw * 128;
                f32x4 bb = *(const f32x4*)(b1 + jr + l4 * 4);
                f32x4 wt = *(const f32x4*)(w1x + jr + l4 * 4);
#pragma unroll
                for (int mt = 0; mt < 2; mt++) {
                    f32x4 a1 = {};
#pragma unroll
                    for (int ks = 0; ks < 2; ks++) {
                        const int k0 = ks * 32 + l4 * 8;
                        bf16x8 a = *(const bf16x8*)(p1 + (((((ks << 2) | l4) ^ rw) & 7) << 4));
                        bf16x8 b = *(const bf16x8*)&xins[lds64(mt * 16 + l15, k0)];
                        a1 = __builtin_amdgcn_mfma_f32_16x16x32_bf16(a, b, a1, 0, 0, 0);
                    }
                    u32x2 pw = {
                        pack2(f2bf(tanh_fast(a1[0] + bb[0] + ts * wt[0])),
                              f2bf(tanh_fast(a1[1] + bb[1] + ts * wt[1]))),
                        pack2(f2bf(tanh_fast(a1[2] + bb[2] + ts * wt[2])),
                              f2bf(tanh_fast(a1[3] + bb[3] + ts * wt[3]))) };
                    *(u32x2*)&h1s[ldso(mt * 16 + l15, jr + l4 * 4)] = pw;
                }
            }
            __syncthreads();  // B1: h1s ready

            // ---- G2: h2^T = W2^T @ h1^T, tanh(+b2) -> h2s ----
            big_gemm(h1s);
#pragma unroll
            for (int jj = 0; jj < 8; jj++) {
                const int jr = (wv * 8 + jj) * 16;
                f32x4 bb = *(const f32x4*)(b2 + jr + l4 * 4);
#pragma unroll
                for (int mt = 0; mt < 2; mt++) {
                    u32x2 pw = {
                        pack2(f2bf(tanh_fast(acc[jj][mt][0] + bb[0])),
                              f2bf(tanh_fast(acc[jj][mt][1] + bb[1]))),
                        pack2(f2bf(tanh_fast(acc[jj][mt][2] + bb[2])),
                              f2bf(tanh_fast(acc[jj][mt][3] + bb[3]))) };
                    *(u32x2*)&h2s[ldso(mt * 16 + l15, jr + l4 * 4)] = pw;
                }
            }
            __syncthreads();  // B2: h2s ready

            // ---- G3: dx^T = W3^T @ h2^T (1 tile/wave, pipelined) ----
            f32x4 acc3 = {};
            {
                const int row3 = (wv >> 1) * 16 + l15;
                const int mt3 = wv & 1;
                auto a3addr = [&](int ks) -> const char* {
                    return (const char*)w3t + (size_t)row3 * 2048 + ((ks >> 1) << 7)
                           + (((((ks << 2) | l4) ^ row3) & 7) << 4);
                };
                bf16x8 ga = *(const bf16x8*)a3addr(0);
                for (int ks = 0; ks < 32; ks += 2) {
                    bf16x8 gb = *(const bf16x8*)a3addr(ks + 1);
                    bf16x8 hb0 = *(const bf16x8*)&h2s[ldso(mt3 * 16 + l15, ks * 32 + l4 * 8)];
                    acc3 = __builtin_amdgcn_mfma_f32_16x16x32_bf16(ga, hb0, acc3, 0, 0, 0);
                    if (ks + 2 < 32) ga = *(const bf16x8*)a3addr(ks + 2);
                    bf16x8 hb1 = *(const bf16x8*)&h2s[ldso(mt3 * 16 + l15, (ks + 1) * 32 + l4 * 8)];
                    acc3 = __builtin_amdgcn_mfma_f32_16x16x32_bf16(gb, hb1, acc3, 0, 0, 0);
                }
            }

            // ---- P4 (same phase; h2s read-only, h1s thread-local RMW):
            //      g3 = W3 @ eps^T, E = W1^T @ eps^T (recomputed, tiny);
            //      g2 = g3*(1-h2^2) -> REGS (packed); me = (1-h1^2)*E -> h1s ----
#pragma unroll
            for (int jj = 0; jj < 8; jj++) {
                const int jr = (wv * 8 + jj) * 16;
                const int rw = jr + l15;
                const char* p3 = (const char*)w3n + rw * 128;
                const char* p1 = (const char*)w1tb + rw * 128;
#pragma unroll
                for (int mt = 0; mt < 2; mt++) {
                    f32x4 ag = {}, ae = {};
#pragma unroll
                    for (int ks = 0; ks < 2; ks++) {
                        const int k0 = ks * 32 + l4 * 8;
                        const int so = (((((ks << 2) | l4) ^ rw) & 7) << 4);
                        bf16x8 be = *(const bf16x8*)&epss[lds64(mt * 16 + l15, k0)];
                        bf16x8 a3 = *(const bf16x8*)(p3 + so);
                        bf16x8 a1 = *(const bf16x8*)(p1 + so);
                        ag = __builtin_amdgcn_mfma_f32_16x16x32_bf16(a3, be, ag, 0, 0, 0);
                        ae = __builtin_amdgcn_mfma_f32_16x16x32_bf16(a1, be, ae, 0, 0, 0);
                    }
                    const int off = ldso(mt * 16 + l15, jr + l4 * 4);
                    u32x2 hw = *(u32x2*)&h2s[off];
                    u32x2 h1w = *(u32x2*)&h1s[off];
                    float h2v[4] = { bf2f((u16)(hw[0] & 0xffff)), bf2f((u16)(hw[0] >> 16)),
                                     bf2f((u16)(hw[1] & 0xffff)), bf2f((u16)(hw[1] >> 16)) };
                    float h1v[4] = { bf2f((u16)(h1w[0] & 0xffff)), bf2f((u16)(h1w[0] >> 16)),
                                     bf2f((u16)(h1w[1] & 0xffff)), bf2f((u16)(h1w[1] >> 16)) };
                    g2p[jj][mt] = (u32x2){
                        pack2(f2bf(ag[0] * (1.f - h2v[0] * h2v[0])),
                              f2bf(ag[1] * (1.f - h2v[1] * h2v[1]))),
                        pack2(f2bf(ag[2] * (1.f - h2v[2] * h2v[2])),
                              f2bf(ag[3] * (1.f - h2v[3] * h2v[3]))) };
                    u32x2 pm = {
                        pack2(f2bf(ae[0] * (1.f - h1v[0] * h1v[0])),
                              f2bf(ae[1] * (1.f - h1v[1] * h1v[1]))),
                        pack2(f2bf(ae[2] * (1.f - h1v[2] * h1v[2])),
                              f2bf(ae[3] * (1.f - h1v[3] * h1v[3]))) };
                    *(u32x2*)&h1s[off] = pm;
                }
            }
            __syncthreads();  // B3: me (h1s) ready

            // ---- P5: q^T = W2^T @ me^T (same w2t frags as G2);
            //          trace partial = sum q .* g2 (register-aligned tiles) ----
            big_gemm(h1s);
            {
                float ts0 = 0.f, ts1 = 0.f;
#pragma unroll
                for (int jj = 0; jj < 8; jj++) {
#pragma unroll
                    for (int mt = 0; mt < 2; mt++) {
                        u32x2 g = g2p[jj][mt];
                        float d = acc[jj][mt][0] * bf2f((u16)(g[0] & 0xffff))
                                + acc[jj][mt][1] * bf2f((u16)(g[0] >> 16))
                                + acc[jj][mt][2] * bf2f((u16)(g[1] & 0xffff))
                                + acc[jj][mt][3] * bf2f((u16)(g[1] >> 16));
                        if (mt == 0) ts0 += d; else ts1 += d;
                    }
                }
                red[l15 * 33 + wv * 4 + l4] = ts0;
                red[(16 + l15) * 33 + wv * 4 + l4] = ts1;
            }
            __syncthreads();  // B4: red ready

            // ---- RK4 combine (in-register state) ----
            {
                const float wacc = (st == 1 || st == 2) ? 2.f : 1.f;
                const float wtmp = (st < 2) ? 0.5f * h : h;
                f32x4 b3v = *(const f32x4*)(b3 + sf);
                float nx[4];
#pragma unroll
                for (int r = 0; r < 4; r++) {
                    float d = acc3[r] + b3v[r];
                    axr[r] = (st == 0 ? 0.f : axr[r]) + wacc * d;
                    if (st == 3) { yxr[r] += h6 * axr[r]; nx[r] = yxr[r]; }
                    else nx[r] = yxr[r] + wtmp * d;
                }
                u32x2 px = { pack2(f2bf(nx[0]), f2bf(nx[1])), pack2(f2bf(nx[2]), f2bf(nx[3])) };
                *(u32x2*)&xins[lds64(sm, sf)] = px;
                if (tid < RM) {
                    float tr = 0.f;
#pragma unroll
                    for (int c = 0; c < 32; c++) tr += red[tid * 33 + c];
                    al = (st == 0 ? 0.f : al) + wacc * (-tr);
                    if (st == 3) yl += h6 * al;
                }
            }
            __syncthreads();  // B5: xins ready; h1s free for next G1
        }
    }

    // ---- output ----
    {
        f32x4 zv = { yxr[0], yxr[1], yxr[2], yxr[3] };
        *(f32x4*)(outp + (size_t)(m0 + sm) * FEAT + sf) = zv;
        if (tid < RM) outp[(size_t)BATCH * FEAT + m0 + tid] = yl;
    }
}

// ---- weight prep (once per call; tiny) ----
__global__ void cast_bf(const float* __restrict__ in, u16* __restrict__ out,
                        int n, int W)
{
    int i = blockIdx.x * 256 + threadIdx.x;
    if (i < n) out[swz_off(i / W, i % W, W)] = f2bf(in[i]);
}

// in [R'][C'] fp32 -> out [C'][R'] bf16 swizzled (out rows = in cols)
__global__ void transpose_cast(const float* __restrict__ in, u16* __restrict__ out,
                               int R, int C)
{
    __shared__ float t[32][33];
    int bx = blockIdx.x * 32, by = blockIdx.y * 32;
    int tx = threadIdx.x, ty = threadIdx.y;  // block (32,8)
    for (int i = 0; i < 32; i += 8)
        t[ty + i][tx] = in[(size_t)(by + ty + i) * C + bx + tx];
    __syncthreads();
    for (int i = 0; i < 32; i += 8)
        out[swz_off(bx + ty + i, by + tx, R)] = f2bf(t[tx][ty + i]);
}

extern "C" void kernel_launch(void* const* d_in, const int* in_sizes, int n_in,
                              void* d_out, int out_size, void* d_ws, size_t ws_size,
                              hipStream_t stream)
{
    const float* x   = (const float*)d_in[0];
    const float* W1  = (const float*)d_in[1];
    const float* b1  = (const float*)d_in[2];
    const float* W2  = (const float*)d_in[3];
    const float* b2  = (const float*)d_in[4];
    const float* W3  = (const float*)d_in[5];
    const float* b3  = (const float*)d_in[6];
    const float* eps = (const float*)d_in[7];
    float* out = (float*)d_out;

    char* ws = (char*)d_ws;
    size_t o = 0;
    auto alloc = [&](size_t bytes) { char* p = ws + o; o += (bytes + 255) & ~(size_t)255; return p; };

    u16* w1tb = (u16*)alloc((size_t)HID * FEAT * 2);   // [1024][64] W1[:64]^T
    u16* w2t  = (u16*)alloc((size_t)HID * HID * 2);    // W2^T
    u16* w3n  = (u16*)alloc((size_t)HID * FEAT * 2);   // [1024][64] W3
    u16* w3t  = (u16*)alloc((size_t)FEAT * HID * 2);   // [64][1024] W3^T

    const dim3 blk(256);
    cast_bf<<<dim3((HID * FEAT + 255) / 256), blk, 0, stream>>>(W3, w3n, HID * FEAT, FEAT);
    transpose_cast<<<dim3(HID / 32, HID / 32), dim3(32, 8), 0, stream>>>(W2, w2t, HID, HID);
    transpose_cast<<<dim3(HID / 32, FEAT / 32), dim3(32, 8), 0, stream>>>(W1, w1tb, FEAT, HID);
    transpose_cast<<<dim3(FEAT / 32, HID / 32), dim3(32, 8), 0, stream>>>(W3, w3t, HID, FEAT);

    ffjord_mega<<<dim3(NBLK), dim3(512), 0, stream>>>(
        x, eps,
        w1tb, W1 + (size_t)FEAT * HID, b1,
        w2t, b2,
        w3n, w3t, b3,
        out);
}